// Round 7
// baseline (279.966 us; speedup 1.0000x reference)
//
#include <hip/hip_runtime.h>
#include <cstdint>
#include <cstddef>

// Problem constants (match reference)
#define NS 4000
#define NG 50000
#define NE 250000
#define DIM 128
#define NDST_TOT (NG + NS)          // 54000 combined CSR rows (sg then gs)

typedef __bf16 bf16_t;
typedef bf16_t bf16x8 __attribute__((ext_vector_type(8)));
typedef bf16_t bf16x4 __attribute__((ext_vector_type(4)));
typedef bf16_t bf16x2 __attribute__((ext_vector_type(2)));
typedef float floatx4 __attribute__((ext_vector_type(4)));

// ---------------------------------------------------------------------------
// Phase A0 `prep` = 8 weight transposes + bf16 casts of x_mrna/x_gene
// (pure BW, ~7 us). Runs FIRST so the 5 layer-1 GEMMs can ride along with
// the histogram in `histgemm`.
// ---------------------------------------------------------------------------
#define WT_TOT 143360               // 4*16384 + 2*32768 + 4096 + 8192
#define XM_W 64000                  // 4000*128/8
#define XG_W 800000                 // 50000*128/8
#define PREP_B 3935                 // (WT_TOT + XM_W + XG_W)/256 exactly
struct PArgs {
  const float* W[8]; bf16_t* Wt[8]; int N[8]; int e0[8];
  const float* xm; bf16_t* xbm;
  const float* xg; bf16_t* xbg;
};

__global__ __launch_bounds__(256) void prep(PArgs a) {
  int u = blockIdx.x * 256 + threadIdx.x;
  if (u < WT_TOT) {
    int c = 0;
#pragma unroll
    for (int i = 1; i < 8; i++) if (u >= a.e0[i]) c = i;
    int idx = u - a.e0[c];
    int N = a.N[c];
    int k = idx / N, n = idx - k * N;
    a.Wt[c][n * 128 + k] = (bf16_t)a.W[c][idx];
  } else if (u < WT_TOT + XM_W) {
    int j = (u - WT_TOT) * 8;
    float4 v0 = *reinterpret_cast<const float4*>(a.xm + j);
    float4 v1 = *reinterpret_cast<const float4*>(a.xm + j + 4);
    bf16x8 b;
    b[0] = (bf16_t)v0.x; b[1] = (bf16_t)v0.y; b[2] = (bf16_t)v0.z; b[3] = (bf16_t)v0.w;
    b[4] = (bf16_t)v1.x; b[5] = (bf16_t)v1.y; b[6] = (bf16_t)v1.z; b[7] = (bf16_t)v1.w;
    *reinterpret_cast<bf16x8*>(a.xbm + j) = b;
  } else {
    int j = (u - WT_TOT - XM_W) * 8;
    float4 v0 = *reinterpret_cast<const float4*>(a.xg + j);
    float4 v1 = *reinterpret_cast<const float4*>(a.xg + j + 4);
    bf16x8 b;
    b[0] = (bf16_t)v0.x; b[1] = (bf16_t)v0.y; b[2] = (bf16_t)v0.z; b[3] = (bf16_t)v0.w;
    b[4] = (bf16_t)v1.x; b[5] = (bf16_t)v1.y; b[6] = (bf16_t)v1.z; b[7] = (bf16_t)v1.w;
    *reinterpret_cast<bf16x8*>(a.xbg + j) = b;
  }
}

// ---------------------------------------------------------------------------
// Fused histogram + 5 layer-1 MFMA GEMMs.
// R7: GEMM tile 256->128 rows/block (2 row-tiles/wave, = gemm_multi body):
// R6 measured histgemm 45 us @ 27% occupancy, all pipes idle — the 440
// heavy GEMM blocks (1.7/CU) ran the tail with the machine 3/4 empty and
// this body is VMEM-issue-bound (multi-segment B-gathers/Y-stores), so TLP
// is the only latency hider. 878 GEMM blocks ~= 3.4/CU.
// Blocks [hist0, ...): per-dst degree counts; the atomicAdd return value IS
// the edge's rank (ushort) -> the scatter needs NO atomics.
// ---------------------------------------------------------------------------
#define HIST_B 977                  // ceil(NE/256)
struct HGArgs {
  // hist
  const int* sgd; const int* gsd;
  int* cnt; unsigned short* rank_sg; unsigned short* rank_gs;
  int hist0;                        // first hist block (= #gemm blocks)
  // gemm (5 configs)
  const bf16_t* X[5];
  const bf16_t* Wt[5];
  const float* Bv[5];
  bf16_t* Y[5];
  int M[5];
  int Ncol[5];
  int blk0[5];
};

__global__ __launch_bounds__(256, 4) void histgemm(HGArgs a) {
  if ((int)blockIdx.x >= a.hist0) {
    int e = ((int)blockIdx.x - a.hist0) * 256 + threadIdx.x;
    if (e < NE) {
      a.rank_sg[e] = (unsigned short)atomicAdd(a.cnt + a.sgd[e], 1);
      a.rank_gs[e] = (unsigned short)atomicAdd(a.cnt + NG + a.gsd[e], 1);
    }
    return;
  }
  int bid = blockIdx.x;
  int c = 0;
#pragma unroll
  for (int i = 1; i < 5; i++) if (bid >= a.blk0[i]) c = i;
  const bf16_t* X = a.X[c];
  const bf16_t* Wt = a.Wt[c];
  const float* B = a.Bv[c];
  bf16_t* Y = a.Y[c];
  int M = a.M[c];
  int N = a.Ncol[c];

  int wv = threadIdx.x >> 6, lane = threadIdx.x & 63;
  int m16 = lane & 15, quad = lane >> 4;
  int wrow0 = (bid - a.blk0[c]) * 128 + wv * 32;   // 2 row-tiles of 16 per wave

  bf16x8 afrag[2][4];                              // [row-tile][k-chunk]
#pragma unroll
  for (int rt = 0; rt < 2; rt++) {
    int arow = wrow0 + rt * 16 + m16;
    const bf16_t* xp = X + (size_t)arow * DIM + quad * 8;
#pragma unroll
    for (int kk = 0; kk < 4; kk++) {
      bf16x8 av = {};
      if (arow < M) av = *reinterpret_cast<const bf16x8*>(xp + kk * 32);
      afrag[rt][kk] = av;
    }
  }

  int ncols = N >> 4;
  for (int nt = 0; nt < ncols; nt++) {
    const bf16_t* bptr = Wt + (size_t)(nt * 16 + m16) * DIM + quad * 8;
    bf16x8 bfrag[4];
#pragma unroll
    for (int kk = 0; kk < 4; kk++)
      bfrag[kk] = *reinterpret_cast<const bf16x8*>(bptr + kk * 32);
    float4 bias = *reinterpret_cast<const float4*>(B + nt * 16 + quad * 4);
#pragma unroll
    for (int rt = 0; rt < 2; rt++) {
      floatx4 acc = {0.f, 0.f, 0.f, 0.f};
#pragma unroll
      for (int kk = 0; kk < 4; kk++)
        acc = __builtin_amdgcn_mfma_f32_16x16x32_bf16(bfrag[kk], afrag[rt][kk], acc, 0, 0, 0);
      int row = wrow0 + rt * 16 + m16;
      if (row < M) {
        bf16x4 o;
        o[0] = (bf16_t)(acc[0] + bias.x);
        o[1] = (bf16_t)(acc[1] + bias.y);
        o[2] = (bf16_t)(acc[2] + bias.z);
        o[3] = (bf16_t)(acc[3] + bias.w);
        *reinterpret_cast<bf16x4*>(Y + (size_t)row * N + nt * 16 + quad * 4) = o;
      }
    }
  }
}

// ---------------------------------------------------------------------------
// Single-kernel parallel scan over n=54000 (53 blocks of 1024) via decoupled
// lookback (R5; neutral vs 2-kernel but fewer launches — keep). af[] zeroed
// by the arena memset. NOTE: do NOT replace with a single-block serial scan
// — measured 103 us in an earlier session.
// ---------------------------------------------------------------------------
__global__ __launch_bounds__(1024) void scan_fused(const int* __restrict__ cnt,
                                                   int* __restrict__ rp,
                                                   int* af, int n) {
  __shared__ int wsum[16];
  __shared__ int pfx_s;
  int i = blockIdx.x * 1024 + threadIdx.x;
  int lane = threadIdx.x & 63, w = threadIdx.x >> 6;
  int v = (i < n) ? cnt[i] : 0;
  int x = v;
#pragma unroll
  for (int off = 1; off < 64; off <<= 1) {
    int y = __shfl_up(x, off);
    if (lane >= off) x += y;
  }
  if (lane == 63) wsum[w] = x;
  __syncthreads();
  if (w == 0 && lane < 16) {
    int s = wsum[lane];
#pragma unroll
    for (int off = 1; off < 16; off <<= 1) {
      int y = __shfl_up(s, off);
      if (lane >= off) s += y;
    }
    wsum[lane] = s;
  }
  __syncthreads();
  int incl = x + (w ? wsum[w - 1] : 0);
  if (threadIdx.x == 0) atomicExch(af + blockIdx.x, wsum[15] + 1);  // publish
  if (w == 0) {
    int pred = 0;
    if (lane < (int)blockIdx.x) {               // blockIdx.x <= 52 < 64
      int t;
      while ((t = atomicAdd(af + lane, 0)) == 0) { __builtin_amdgcn_s_sleep(8); }
      pred = t - 1;
    }
#pragma unroll
    for (int off = 32; off > 0; off >>= 1) pred += __shfl_down(pred, off);
    if (lane == 0) pfx_s = pred;
  }
  __syncthreads();
  if (i < n) rp[i] = incl - v + pfx_s;
  if (i == 0) rp[n] = 2 * NE;                   // static total sentinel
}

// ---------------------------------------------------------------------------
// Atomic-free CSR scatter, 4 edges/thread (rank precomputed in histgemm).
// ---------------------------------------------------------------------------
#define SCAT_HALF 245               // ceil(NE/1024)
#define SCAT_B 490                  // 2 relations
struct ScArgs {
  const int* sgd; const int* gsd; const int* sgs; const int* gss;
  const float* easg; const float* eags;
  const int* rp; const unsigned short* rank_sg; const unsigned short* rank_gs;
  uint2* meta;
};

__global__ __launch_bounds__(256) void scat(ScArgs a) {
  int rel = (int)blockIdx.x >= SCAT_HALF;
  int b = (int)blockIdx.x - (rel ? SCAT_HALF : 0);
  int t4 = (b * 256 + (int)threadIdx.x) * 4;
  if (t4 < NE) {                            // NE % 4 == 0: all-or-nothing
    const int* dp = rel ? a.gsd : a.sgd;
    const int* sp = rel ? a.gss : a.sgs;
    const float* ep = rel ? a.eags : a.easg;
    const unsigned short* rk = rel ? a.rank_gs : a.rank_sg;
    const int* rpb = a.rp + (rel ? NG : 0);
    int4 d4 = *reinterpret_cast<const int4*>(dp + t4);
    int4 s4 = *reinterpret_cast<const int4*>(sp + t4);
    float4 e4 = *reinterpret_cast<const float4*>(ep + t4);
    ushort4 r4 = *reinterpret_cast<const ushort4*>(rk + t4);
    int p0 = rpb[d4.x] + (int)r4.x;         // 4 independent gather chains
    int p1 = rpb[d4.y] + (int)r4.y;
    int p2 = rpb[d4.z] + (int)r4.z;
    int p3 = rpb[d4.w] + (int)r4.w;
    uint2 v0, v1, v2, v3;
    v0.x = (unsigned)s4.x; v0.y = __float_as_uint(e4.x);
    v1.x = (unsigned)s4.y; v1.y = __float_as_uint(e4.y);
    v2.x = (unsigned)s4.z; v2.y = __float_as_uint(e4.z);
    v3.x = (unsigned)s4.w; v3.y = __float_as_uint(e4.w);
    a.meta[p0] = v0;
    a.meta[p1] = v1;
    a.meta[p2] = v2;
    a.meta[p3] = v3;
  }
}

// ---------------------------------------------------------------------------
// Multi-config MFMA GEMM (phase D), runtime column count. R2 structure,
// 2 row-tiles per wave (128 rows/block) to keep >=450 blocks.
// ---------------------------------------------------------------------------
template <int NCFG>
struct GArgs {
  const bf16_t* X[NCFG];
  const bf16_t* Wt[NCFG];
  const float* Bv[NCFG];
  bf16_t* Y[NCFG];
  int M[NCFG];
  int Ncol[NCFG];
  int blk0[NCFG];
};

template <int NCFG>
__global__ __launch_bounds__(256, 4) void gemm_multi(GArgs<NCFG> a) {
  int c = 0;
#pragma unroll
  for (int i = 1; i < NCFG; i++) if ((int)blockIdx.x >= a.blk0[i]) c = i;
  const bf16_t* X = a.X[c];
  const bf16_t* Wt = a.Wt[c];
  const float* B = a.Bv[c];
  bf16_t* Y = a.Y[c];
  int M = a.M[c];
  int N = a.Ncol[c];

  int wv = threadIdx.x >> 6, lane = threadIdx.x & 63;
  int m16 = lane & 15, quad = lane >> 4;
  int wrow0 = ((int)blockIdx.x - a.blk0[c]) * 128 + wv * 32;  // 2 row-tiles

  bf16x8 afrag[2][4];
#pragma unroll
  for (int rt = 0; rt < 2; rt++) {
    int arow = wrow0 + rt * 16 + m16;
    const bf16_t* xp = X + (size_t)arow * DIM + quad * 8;
#pragma unroll
    for (int kk = 0; kk < 4; kk++) {
      bf16x8 av = {};
      if (arow < M) av = *reinterpret_cast<const bf16x8*>(xp + kk * 32);
      afrag[rt][kk] = av;
    }
  }

  int ncols = N >> 4;
  for (int nt = 0; nt < ncols; nt++) {
    const bf16_t* bptr = Wt + (size_t)(nt * 16 + m16) * DIM + quad * 8;
    bf16x8 bfrag[4];
#pragma unroll
    for (int kk = 0; kk < 4; kk++)
      bfrag[kk] = *reinterpret_cast<const bf16x8*>(bptr + kk * 32);
    float4 bias = *reinterpret_cast<const float4*>(B + nt * 16 + quad * 4);
#pragma unroll
    for (int rt = 0; rt < 2; rt++) {
      floatx4 acc = {0.f, 0.f, 0.f, 0.f};
#pragma unroll
      for (int kk = 0; kk < 4; kk++)
        acc = __builtin_amdgcn_mfma_f32_16x16x32_bf16(bfrag[kk], afrag[rt][kk], acc, 0, 0, 0);
      int row = wrow0 + rt * 16 + m16;
      if (row < M) {
        bf16x4 o;
        o[0] = (bf16_t)(acc[0] + bias.x);
        o[1] = (bf16_t)(acc[1] + bias.y);
        o[2] = (bf16_t)(acc[2] + bias.z);
        o[3] = (bf16_t)(acc[3] + bias.w);
        *reinterpret_cast<bf16x4*>(Y + (size_t)row * N + nt * 16 + quad * 4) = o;
      }
    }
  }
}

// ---------------------------------------------------------------------------
// Fused phase-C gather, GROUP-PER-DST layout (NC=128, 8 ch per lane,
// 16-lane groups; head = gl>>2 -> logit reduce = 2 shfls, no dst select).
// Blocks [0, SGB): sg — 4 waves/block, each wave 4 dsts, one per group.
// Blocks [SGB, SGB+NS): gs — one block per dst; 16 groups walk LDS-staged
//   edges (block-coalesced meta stage), partials combined in LDS.
// NOTE: exact R2 form. R3 (2-chain unrolls inside this structure) and R4
// (wave-per-dst, no LDS) BOTH regressed ~10 us — do not re-attempt without
// per-kernel timing evidence. Also: no readfirstlane+scalar branch per edge
// (earlier measured 73 us vs 55).
// ---------------------------------------------------------------------------
#define SGB 3125                    // 50000 dsts / (4 waves * 4 dsts)
__global__ __launch_bounds__(256) void gatC(
    const int* __restrict__ rp, const uint2* __restrict__ meta,
    const float* __restrict__ WeS, const float* __restrict__ attS,
    const float* __restrict__ boS,
    const bf16_t* __restrict__ xlS, const bf16_t* __restrict__ xrS,
    bf16_t* __restrict__ outS,
    const float* __restrict__ WeG, const float* __restrict__ attG,
    const float* __restrict__ boG,
    const bf16_t* __restrict__ xlG, const bf16_t* __restrict__ xrG,
    const bf16_t* __restrict__ slG, bf16_t* __restrict__ outG) {
  __shared__ uint2 smeta[256];
  __shared__ float lacc[16][128];
  __shared__ float lden[16][4];
  int lane = threadIdx.x & 63, wv = threadIdx.x >> 6;
  int gl = lane & 15, grp = lane >> 4;

  if (blockIdx.x < SGB) {
    // ---------------- sg: 4 dsts per wave, one per 16-lane group ----------
    int wid = blockIdx.x * 4 + wv;
    int d0 = wid * 4;
    int q = lane < 5 ? lane : 0;
    int rv = rp[d0 + q];
    int beg = __shfl(rv, grp), end = __shfl(rv, grp + 1);
    int dst = d0 + grp;

    float wev[8], atv[8], xrv[8], acc[8];
    *reinterpret_cast<float4*>(wev) = *reinterpret_cast<const float4*>(WeS + gl * 8);
    *reinterpret_cast<float4*>(wev + 4) = *reinterpret_cast<const float4*>(WeS + gl * 8 + 4);
    *reinterpret_cast<float4*>(atv) = *reinterpret_cast<const float4*>(attS + gl * 8);
    *reinterpret_cast<float4*>(atv + 4) = *reinterpret_cast<const float4*>(attS + gl * 8 + 4);
    bf16x8 xrb = *reinterpret_cast<const bf16x8*>(xrS + (size_t)dst * 128 + gl * 8);
#pragma unroll
    for (int v = 0; v < 8; v++) { xrv[v] = (float)xrb[v]; acc[v] = 0.f; }
    float den = 0.f;

    for (int i0 = beg; i0 < end; i0 += 16) {
      int cnt = min(16, end - i0);
      int s_l = 0; float ea_l = 0.f;
      if (gl < cnt) {
        uint2 mv = meta[i0 + gl];
        s_l = (int)mv.x; ea_l = __uint_as_float(mv.y);
      }
      // 1-deep prefetch of next edge's row
      int base = lane & 48;
      float ea = __shfl(ea_l, base);
      bf16x8 xlb = *reinterpret_cast<const bf16x8*>(
          xlS + (size_t)__shfl(s_l, base) * 128 + gl * 8);
      for (int k = 0; k < cnt; k++) {
        bf16x8 cur = xlb;
        float eac = ea;
        if (k + 1 < cnt) {
          ea = __shfl(ea_l, base + k + 1);
          xlb = *reinterpret_cast<const bf16x8*>(
              xlS + (size_t)__shfl(s_l, base + k + 1) * 128 + gl * 8);
        }
        float p = 0.f, xf[8];
#pragma unroll
        for (int v = 0; v < 8; v++) {
          xf[v] = (float)cur[v];
          float z = fmaf(eac, wev[v], xrv[v]) + xf[v];
          z = z > 0.f ? z : 0.2f * z;            // leaky_relu(., 0.2)
          p = fmaf(z, atv[v], p);
        }
        p += __shfl_xor(p, 1);
        p += __shfl_xor(p, 2);                   // head-wide logit (4 lanes)
        float ex = __expf(p);
        den += ex;
#pragma unroll
        for (int v = 0; v < 8; v++) acc[v] = fmaf(ex, xf[v], acc[v]);
      }
    }
    float inv = den > 0.f ? 1.f / den : 0.f;
    bf16x8 o;
#pragma unroll
    for (int v = 0; v < 8; v++) {
      float val = acc[v] * inv + boS[gl * 8 + v];
      o[v] = (bf16_t)(val > 0.f ? val : 0.f);
    }
    *reinterpret_cast<bf16x8*>(outS + (size_t)dst * 128 + gl * 8) = o;
  } else {
    // ---------------- gs: one block per dst, 16 groups over LDS stage -----
    int d = (int)blockIdx.x - SGB;
    const int* rpg = rp + NG;
    int G = wv * 4 + grp;
    int tid = threadIdx.x;

    float wev[8], atv[8], xrv[8], acc[8];
    *reinterpret_cast<float4*>(wev) = *reinterpret_cast<const float4*>(WeG + gl * 8);
    *reinterpret_cast<float4*>(wev + 4) = *reinterpret_cast<const float4*>(WeG + gl * 8 + 4);
    *reinterpret_cast<float4*>(atv) = *reinterpret_cast<const float4*>(attG + gl * 8);
    *reinterpret_cast<float4*>(atv + 4) = *reinterpret_cast<const float4*>(attG + gl * 8 + 4);
    bf16x8 xrb = *reinterpret_cast<const bf16x8*>(xrG + (size_t)d * 128 + gl * 8);
#pragma unroll
    for (int v = 0; v < 8; v++) { xrv[v] = (float)xrb[v]; acc[v] = 0.f; }
    float den = 0.f;

    int beg = rpg[d], end = rpg[d + 1];
    for (int base = beg; base < end; base += 256) {
      int cntb = min(256, end - base);
      __syncthreads();
      if (tid < cntb) smeta[tid] = meta[base + tid];
      __syncthreads();
      int e = G;
      uint2 mv; bf16x8 xlb;
      if (e < cntb) {
        mv = smeta[e];
        xlb = *reinterpret_cast<const bf16x8*>(xlG + (size_t)mv.x * 128 + gl * 8);
      }
      while (e < cntb) {
        bf16x8 cur = xlb;
        float eac = __uint_as_float(mv.y);
        int en = e + 16;
        if (en < cntb) {
          mv = smeta[en];
          xlb = *reinterpret_cast<const bf16x8*>(xlG + (size_t)mv.x * 128 + gl * 8);
        }
        float p = 0.f, xf[8];
#pragma unroll
        for (int v = 0; v < 8; v++) {
          xf[v] = (float)cur[v];
          float z = fmaf(eac, wev[v], xrv[v]) + xf[v];
          z = z > 0.f ? z : 0.2f * z;
          p = fmaf(z, atv[v], p);
        }
        p += __shfl_xor(p, 1);
        p += __shfl_xor(p, 2);
        float ex = __expf(p);
        den += ex;
#pragma unroll
        for (int v = 0; v < 8; v++) acc[v] = fmaf(ex, xf[v], acc[v]);
        e = en;
      }
    }
#pragma unroll
    for (int v = 0; v < 8; v++) lacc[G][gl * 8 + v] = acc[v];
    if ((gl & 3) == 0) lden[G][gl >> 2] = den;
    __syncthreads();
    if (wv != 0) return;
    int ch = lane * 2;
    int h = lane >> 4;
    float a0 = 0.f, a1 = 0.f, dh = 0.f;
#pragma unroll
    for (int g2 = 0; g2 < 16; g2++) {
      a0 += lacc[g2][ch];
      a1 += lacc[g2][ch + 1];
      dh += lden[g2][h];
    }
    float inv = dh > 0.f ? 1.f / dh : 0.f;
    float v0 = a0 * inv + boG[ch] + (float)slG[(size_t)d * 32 + (ch & 31)];
    float v1 = a1 * inv + boG[ch + 1] + (float)slG[(size_t)d * 32 + ((ch + 1) & 31)];
    bf16x2 o;
    o[0] = (bf16_t)(v0 > 0.f ? v0 : 0.f);
    o[1] = (bf16_t)(v1 > 0.f ? v1 : 0.f);
    *reinterpret_cast<bf16x2*>(outG + (size_t)d * 128 + ch) = o;
  }
}

// ---------------------------------------------------------------------------
// Phase-E gather: one block per dst; 16 groups of 16 lanes, 16 ch/lane
// (NC=256); LDS-staged edges + LDS combine; head-mean epilogue -> fp32 out.
// Exact R2 form (see gatC note: R3/R4 variants regressed).
// ---------------------------------------------------------------------------
__global__ __launch_bounds__(256) void gatE(
    const int* __restrict__ rp, const uint2* __restrict__ meta,
    const float* __restrict__ We, const float* __restrict__ att,
    const bf16_t* __restrict__ xl, const bf16_t* __restrict__ xr,
    const float* __restrict__ bo, const bf16_t* __restrict__ sl,
    float* __restrict__ out) {
  __shared__ uint2 smeta[256];
  __shared__ float lacc[16][256];
  __shared__ float lden[16][4];
  int lane = threadIdx.x & 63, wv = threadIdx.x >> 6;
  int gl = lane & 15, grp = lane >> 4;
  int G = wv * 4 + grp;
  int tid = threadIdx.x;
  int d = blockIdx.x;

  float wev[16], atv[16], xrv[16], acc[16];
#pragma unroll
  for (int b = 0; b < 4; b++) {
    *reinterpret_cast<float4*>(wev + b * 4) =
        *reinterpret_cast<const float4*>(We + gl * 16 + b * 4);
    *reinterpret_cast<float4*>(atv + b * 4) =
        *reinterpret_cast<const float4*>(att + gl * 16 + b * 4);
  }
  {
    bf16x8 r0 = *reinterpret_cast<const bf16x8*>(xr + (size_t)d * 256 + gl * 16);
    bf16x8 r1 = *reinterpret_cast<const bf16x8*>(xr + (size_t)d * 256 + gl * 16 + 8);
#pragma unroll
    for (int v = 0; v < 8; v++) { xrv[v] = (float)r0[v]; xrv[v + 8] = (float)r1[v]; }
  }
#pragma unroll
  for (int v = 0; v < 16; v++) acc[v] = 0.f;
  float den = 0.f;

  int beg = rp[d], end = rp[d + 1];
  for (int base = beg; base < end; base += 256) {
    int cntb = min(256, end - base);
    __syncthreads();
    if (tid < cntb) smeta[tid] = meta[base + tid];
    __syncthreads();
    int e = G;
    uint2 mv; bf16x8 x0, x1;
    if (e < cntb) {
      mv = smeta[e];
      x0 = *reinterpret_cast<const bf16x8*>(xl + (size_t)mv.x * 256 + gl * 16);
      x1 = *reinterpret_cast<const bf16x8*>(xl + (size_t)mv.x * 256 + gl * 16 + 8);
    }
    while (e < cntb) {
      bf16x8 c0 = x0, c1 = x1;
      float eac = __uint_as_float(mv.y);
      int en = e + 16;
      if (en < cntb) {
        mv = smeta[en];
        x0 = *reinterpret_cast<const bf16x8*>(xl + (size_t)mv.x * 256 + gl * 16);
        x1 = *reinterpret_cast<const bf16x8*>(xl + (size_t)mv.x * 256 + gl * 16 + 8);
      }
      float p = 0.f, xf[16];
#pragma unroll
      for (int v = 0; v < 8; v++) { xf[v] = (float)c0[v]; xf[v + 8] = (float)c1[v]; }
#pragma unroll
      for (int v = 0; v < 16; v++) {
        float z = fmaf(eac, wev[v], xrv[v]) + xf[v];
        z = z > 0.f ? z : 0.2f * z;              // leaky_relu(., 0.2)
        p = fmaf(z, atv[v], p);
      }
      p += __shfl_xor(p, 1);
      p += __shfl_xor(p, 2);                     // head-wide logit (4 lanes)
      float ex = __expf(p);
      den += ex;
#pragma unroll
      for (int v = 0; v < 16; v++) acc[v] = fmaf(ex, xf[v], acc[v]);
      e = en;
    }
  }
#pragma unroll
  for (int v = 0; v < 16; v++) lacc[G][gl * 16 + v] = acc[v];
  if ((gl & 3) == 0) lden[G][gl >> 2] = den;
  __syncthreads();
  if (wv != 0) return;
  int ch = lane * 4;
  int h = lane >> 4;
  float a[4] = {0.f, 0.f, 0.f, 0.f};
  float dh = 0.f;
#pragma unroll
  for (int g2 = 0; g2 < 16; g2++) {
#pragma unroll
    for (int v = 0; v < 4; v++) a[v] += lacc[g2][ch + v];
    dh += lden[g2][h];
  }
  float inv = dh > 0.f ? 1.f / dh : 0.f;
#pragma unroll
  for (int v = 0; v < 4; v++) {
    float s_ = a[v] * inv;
    s_ += __shfl_xor(s_, 16);
    s_ += __shfl_xor(s_, 32);                    // sum over the 4 heads
    if (lane < 16) {
      int c = (lane & 15) * 4 + v;
      float val = 0.25f * s_ + bo[c] + (float)sl[(size_t)d * 64 + c];
      out[(size_t)d * 64 + c] = val > 0.f ? val : 0.f;
    }
  }
}

// ---------------------------------------------------------------------------

static inline int nblk(long long threads) { return (int)((threads + 255) / 256); }
static inline int nrow(int M, int R) { return (M + R - 1) / R; }

extern "C" void kernel_launch(void* const* d_in, const int* in_sizes, int n_in,
                              void* d_out, int out_size, void* d_ws, size_t ws_size,
                              hipStream_t stream) {
  const float* x_mrna = (const float*)d_in[0];
  const float* x_gene = (const float*)d_in[1];
  const int* sg_src = (const int*)d_in[2];
  const int* sg_dst = (const int*)d_in[3];
  const int* gs_src = (const int*)d_in[4];
  const int* gs_dst = (const int*)d_in[5];
  const float* ea_sg = (const float*)d_in[6];
  const float* ea_gs = (const float*)d_in[7];
  const float* Wl1_sg = (const float*)d_in[8];
  const float* bl1_sg = (const float*)d_in[9];
  const float* Wr1_sg = (const float*)d_in[10];
  const float* br1_sg = (const float*)d_in[11];
  const float* We1_sg = (const float*)d_in[12];
  const float* att1_sg = (const float*)d_in[13];
  const float* bo1_sg = (const float*)d_in[14];
  const float* Wl1_gs = (const float*)d_in[15];
  const float* bl1_gs = (const float*)d_in[16];
  const float* Wr1_gs = (const float*)d_in[17];
  const float* br1_gs = (const float*)d_in[18];
  const float* We1_gs = (const float*)d_in[19];
  const float* att1_gs = (const float*)d_in[20];
  const float* bo1_gs = (const float*)d_in[21];
  const float* Wl3_gs = (const float*)d_in[22];
  const float* bl3_gs = (const float*)d_in[23];
  const float* Wr3_gs = (const float*)d_in[24];
  const float* br3_gs = (const float*)d_in[25];
  const float* We3_gs = (const float*)d_in[26];
  const float* att3_gs = (const float*)d_in[27];
  const float* bo3_gs = (const float*)d_in[28];
  const float* Wsl1 = (const float*)d_in[29];
  const float* bsl1 = (const float*)d_in[30];
  const float* Wsl3 = (const float*)d_in[31];
  const float* bsl3 = (const float*)d_in[32];

  // ---- workspace arena (fp32 element offsets), bf16 throughout ----
  float* ws = (float*)d_ws;
  bf16_t* xl1_gs = (bf16_t*)(ws + 0);        // bf16[50000*128] dead after C
  bf16_t* xl1_sg = (bf16_t*)(ws + 3200000);  // bf16[4000*128]  dead after C
  bf16_t* xr1_sg = (bf16_t*)(ws + 3456000);  // bf16[50000*128] dead after C
  bf16_t* xr1_gs = (bf16_t*)(ws + 6656000);  // bf16[4000*128]  dead after C
  bf16_t* xl3    = (bf16_t*)(ws + 0);        // bf16[50000*256] aliases [0,6.4M)
  bf16_t* xr3    = (bf16_t*)(ws + 6400000);  // bf16[4000*256]  aliases tail
  bf16_t* xb_mrna = (bf16_t*)(ws + 6912000); // bf16[4000*128]
  bf16_t* xb_gene = (bf16_t*)(ws + 7168000); // bf16[50000*128]
  bf16_t* x1_gene = (bf16_t*)(ws + 10368000);// bf16[50000*128]
  bf16_t* x1_mrna = (bf16_t*)(ws + 13568000);// bf16[4000*128]
  bf16_t* sl1    = (bf16_t*)(ws + 13824000); // bf16[4000*32]
  bf16_t* sl3    = (bf16_t*)(ws + 13856000); // bf16[4000*64]
  int*   ib      = (int*)(ws + 13920000);
  int* cnt  = ib + 0;                   // [54000] zeroed by memset
  int* af   = ib + 54000;               // [64] lookback agg+flag, zeroed too
  int* rpc  = ib + 54064;               // [54001]
  unsigned short* rank_sg = (unsigned short*)(ib + 108066);  // [250000]
  unsigned short* rank_gs = (unsigned short*)(ib + 233066);  // [250000]
  uint2* meta = (uint2*)(ib + 358066);  // [500000] packed (src, ea), 8B-aligned
  bf16_t* wtb = (bf16_t*)(ib + 1358066);// [143360] bf16 transposed weights
  // end: ib + 1429746 ints -> total ~61.4 MB

  bf16_t* wt_l1sg = wtb + 0;
  bf16_t* wt_r1sg = wtb + 16384;
  bf16_t* wt_l1gs = wtb + 32768;
  bf16_t* wt_r1gs = wtb + 49152;
  bf16_t* wt_l3   = wtb + 65536;   // [256*128]
  bf16_t* wt_r3   = wtb + 98304;   // [256*128]
  bf16_t* wt_sl1  = wtb + 131072;  // [32*128]
  bf16_t* wt_sl3  = wtb + 135168;  // [64*128]

  // zero histogram counters + lookback flags (ws poisoned 0xAA per call)
  hipMemsetAsync(cnt, 0, (54000 + 64) * sizeof(int), stream);

  // ---- phase A0: weight transposes + bf16 casts (feeds the L1 GEMMs) ----
  {
    PArgs pa;
    const float* Wsrc[8] = {Wl1_sg, Wr1_sg, Wl1_gs, Wr1_gs, Wl3_gs, Wr3_gs, Wsl1, Wsl3};
    bf16_t* Wdst[8] = {wt_l1sg, wt_r1sg, wt_l1gs, wt_r1gs, wt_l3, wt_r3, wt_sl1, wt_sl3};
    int Nn[8] = {128, 128, 128, 128, 256, 256, 32, 64};
    int e0[8] = {0, 16384, 32768, 49152, 65536, 98304, 131072, 135168};
    for (int i = 0; i < 8; i++) { pa.W[i] = Wsrc[i]; pa.Wt[i] = Wdst[i]; pa.N[i] = Nn[i]; pa.e0[i] = e0[i]; }
    pa.xm = x_mrna; pa.xbm = xb_mrna;
    pa.xg = x_gene; pa.xbg = xb_gene;
    prep<<<PREP_B, 256, 0, stream>>>(pa);
  }

  // ---- phase A1: histogram(+rank) OVERLAPPED with the 5 L1 GEMMs ----
  {
    HGArgs hg;
    hg.sgd = sg_dst; hg.gsd = gs_dst;
    hg.cnt = cnt; hg.rank_sg = rank_sg; hg.rank_gs = rank_gs;
    const bf16_t* Xs[5] = {xb_mrna, xb_gene, xb_gene, xb_mrna, xb_mrna};
    const bf16_t* Ws[5] = {wt_l1sg, wt_r1sg, wt_l1gs, wt_r1gs, wt_sl1};
    const float* Bs[5] = {bl1_sg, br1_sg, bl1_gs, br1_gs, bsl1};
    bf16_t* Ys[5] = {xl1_sg, xr1_sg, xl1_gs, xr1_gs, sl1};
    int Ms[5] = {NS, NG, NG, NS, NS};
    int Ns[5] = {128, 128, 128, 128, 32};
    int b0 = 0;
    for (int i = 0; i < 5; i++) {
      hg.X[i] = Xs[i]; hg.Wt[i] = Ws[i]; hg.Bv[i] = Bs[i]; hg.Y[i] = Ys[i];
      hg.M[i] = Ms[i]; hg.Ncol[i] = Ns[i]; hg.blk0[i] = b0;
      b0 += nrow(Ms[i], 128);
    }
    hg.hist0 = b0;                                   // 878
    histgemm<<<b0 + HIST_B, 256, 0, stream>>>(hg);   // 878 + 977 blocks
  }

  // ---- phase A2: single-kernel lookback scan ----
  int nchunks = (NDST_TOT + 1023) / 1024;            // 53
  scan_fused<<<nchunks, 1024, 0, stream>>>(cnt, rpc, af, NDST_TOT);

  // ---- phase B: atomic-free scatter (4 edges/thread) ----
  {
    ScArgs sa;
    sa.sgd = sg_dst; sa.gsd = gs_dst; sa.sgs = sg_src; sa.gss = gs_src;
    sa.easg = ea_sg; sa.eags = ea_gs;
    sa.rp = rpc; sa.rank_sg = rank_sg; sa.rank_gs = rank_gs; sa.meta = meta;
    scat<<<SCAT_B, 256, 0, stream>>>(sa);            // 490 blocks
  }

  // ---- phase C: fused layer-1 gathers ----
  gatC<<<SGB + NS, 256, 0, stream>>>(
      rpc, meta,
      We1_sg, att1_sg, bo1_sg, xl1_sg, xr1_sg, x1_gene,
      We1_gs, att1_gs, bo1_gs, xl1_gs, xr1_gs, sl1, x1_mrna);

  // ---- phase D: 3 fused layer-3 GEMMs (incl. sl3), 128 rows/block ----
  {
    GArgs<3> ga;
    const bf16_t* Xs[3] = {x1_gene, x1_mrna, x1_mrna};
    const bf16_t* Ws[3] = {wt_l3, wt_r3, wt_sl3};
    const float* Bs[3] = {bl3_gs, br3_gs, bsl3};
    bf16_t* Ys[3] = {xl3, xr3, sl3};
    int Ms[3] = {NG, NS, NS};
    int Ns[3] = {256, 256, 64};
    int b0 = 0;
    for (int i = 0; i < 3; i++) {
      ga.X[i] = Xs[i]; ga.Wt[i] = Ws[i]; ga.Bv[i] = Bs[i]; ga.Y[i] = Ys[i];
      ga.M[i] = Ms[i]; ga.Ncol[i] = Ns[i]; ga.blk0[i] = b0;
      b0 += nrow(Ms[i], 128);
    }
    gemm_multi<3><<<b0, 256, 0, stream>>>(ga);   // 455 blocks
  }

  // ---- phase E: layer-3 gather (head-mean/self-loop/relu) -> d_out ----
  gatE<<<NS, 256, 0, stream>>>(rpc + NG, meta, We3_gs, att3_gs,
                               xl3, xr3, bo3_gs, sl3, (float*)d_out);
}

// Round 9
// 272.292 us; speedup vs baseline: 1.0282x; 1.0282x over previous
//
#include <hip/hip_runtime.h>
#include <cstdint>
#include <cstddef>

// Problem constants (match reference)
#define NS 4000
#define NG 50000
#define NE 250000
#define DIM 128
#define NDST_TOT (NG + NS)          // 54000 combined CSR rows (sg then gs)

typedef __bf16 bf16_t;
typedef bf16_t bf16x8 __attribute__((ext_vector_type(8)));
typedef bf16_t bf16x4 __attribute__((ext_vector_type(4)));
typedef bf16_t bf16x2 __attribute__((ext_vector_type(2)));
typedef float floatx4 __attribute__((ext_vector_type(4)));

// ---------------------------------------------------------------------------
// Phase A0 `prep` = 8 weight transposes + bf16 casts of x_mrna/x_gene
// (pure BW, ~7 us). Runs FIRST so the 5 layer-1 GEMMs can ride along with
// the histogram in `histgemm`.
// ---------------------------------------------------------------------------
#define WT_TOT 143360               // 4*16384 + 2*32768 + 4096 + 8192
#define XM_W 64000                  // 4000*128/8
#define XG_W 800000                 // 50000*128/8
#define PREP_B 3935                 // (WT_TOT + XM_W + XG_W)/256 exactly
struct PArgs {
  const float* W[8]; bf16_t* Wt[8]; int N[8]; int e0[8];
  const float* xm; bf16_t* xbm;
  const float* xg; bf16_t* xbg;
};

__global__ __launch_bounds__(256) void prep(PArgs a) {
  int u = blockIdx.x * 256 + threadIdx.x;
  if (u < WT_TOT) {
    int c = 0;
#pragma unroll
    for (int i = 1; i < 8; i++) if (u >= a.e0[i]) c = i;
    int idx = u - a.e0[c];
    int N = a.N[c];
    int k = idx / N, n = idx - k * N;
    a.Wt[c][n * 128 + k] = (bf16_t)a.W[c][idx];
  } else if (u < WT_TOT + XM_W) {
    int j = (u - WT_TOT) * 8;
    float4 v0 = *reinterpret_cast<const float4*>(a.xm + j);
    float4 v1 = *reinterpret_cast<const float4*>(a.xm + j + 4);
    bf16x8 b;
    b[0] = (bf16_t)v0.x; b[1] = (bf16_t)v0.y; b[2] = (bf16_t)v0.z; b[3] = (bf16_t)v0.w;
    b[4] = (bf16_t)v1.x; b[5] = (bf16_t)v1.y; b[6] = (bf16_t)v1.z; b[7] = (bf16_t)v1.w;
    *reinterpret_cast<bf16x8*>(a.xbm + j) = b;
  } else {
    int j = (u - WT_TOT - XM_W) * 8;
    float4 v0 = *reinterpret_cast<const float4*>(a.xg + j);
    float4 v1 = *reinterpret_cast<const float4*>(a.xg + j + 4);
    bf16x8 b;
    b[0] = (bf16_t)v0.x; b[1] = (bf16_t)v0.y; b[2] = (bf16_t)v0.z; b[3] = (bf16_t)v0.w;
    b[4] = (bf16_t)v1.x; b[5] = (bf16_t)v1.y; b[6] = (bf16_t)v1.z; b[7] = (bf16_t)v1.w;
    *reinterpret_cast<bf16x8*>(a.xbg + j) = b;
  }
}

// ---------------------------------------------------------------------------
// Fused histogram + 5 layer-1 MFMA GEMMs.
// R8: back to 256-row tiles (R6's 440 blocks, measured 45.0 vs R7's 878 @
// 48.3 — occupancy was NOT the limiter) + LDS-STAGED Wt: R6/R7 both show
// all pipes idle at 27% AND 49% occupancy -> the kernel is L2/TA
// transaction-bound. The B-fragment loads were 16-segment strided gathers
// (16 rows x 256B stride) per instruction; staging Wt once per block
// (coalesced, XOR-swizzled byte^=(row&7)<<4 so strided ds_read_b128 is
// conflict-free per G4) turns them into single LDS reads and reads Wt from
// L2 exactly once per block. Bit-identical numerics.
// Blocks [hist0, ...): per-dst degree counts; the atomicAdd return value IS
// the edge's rank (ushort) -> the scatter needs NO atomics.
// ---------------------------------------------------------------------------
#define HIST_B 977                  // ceil(NE/256)
struct HGArgs {
  // hist
  const int* sgd; const int* gsd;
  int* cnt; unsigned short* rank_sg; unsigned short* rank_gs;
  int hist0;                        // first hist block (= #gemm blocks)
  // gemm (5 configs)
  const bf16_t* X[5];
  const bf16_t* Wt[5];
  const float* Bv[5];
  bf16_t* Y[5];
  int M[5];
  int Ncol[5];
  int blk0[5];
};

__global__ __launch_bounds__(256, 4) void histgemm(HGArgs a) {
  __shared__ bf16_t swt[16384];     // 32KB: up to N=128 cols x 128 k
  if ((int)blockIdx.x >= a.hist0) {
    int e = ((int)blockIdx.x - a.hist0) * 256 + threadIdx.x;
    if (e < NE) {
      a.rank_sg[e] = (unsigned short)atomicAdd(a.cnt + a.sgd[e], 1);
      a.rank_gs[e] = (unsigned short)atomicAdd(a.cnt + NG + a.gsd[e], 1);
    }
    return;
  }
  int bid = blockIdx.x;
  int c = 0;
#pragma unroll
  for (int i = 1; i < 5; i++) if (bid >= a.blk0[i]) c = i;
  const bf16_t* X = a.X[c];
  const bf16_t* Wt = a.Wt[c];
  const float* B = a.Bv[c];
  bf16_t* Y = a.Y[c];
  int M = a.M[c];
  int N = a.Ncol[c];

  // ---- stage Wt[N][128] into LDS, XOR-swizzled within each 256B row ----
  {
    int nbytes = N * 256;                          // N rows x 128 bf16
    for (int off = (int)threadIdx.x * 16; off < nbytes; off += 256 * 16) {
      int row = off >> 8;
      int dst = off ^ ((row & 7) << 4);
      *reinterpret_cast<bf16x8*>((char*)swt + dst) =
          *reinterpret_cast<const bf16x8*>((const char*)Wt + off);
    }
  }
  __syncthreads();

  int wv = threadIdx.x >> 6, lane = threadIdx.x & 63;
  int m16 = lane & 15, quad = lane >> 4;
  int wrow0 = (bid - a.blk0[c]) * 256 + wv * 64;   // 4 row-tiles of 16 per wave

  bf16x8 afrag[4][4];                              // [row-tile][k-chunk]
#pragma unroll
  for (int rt = 0; rt < 4; rt++) {
    int arow = wrow0 + rt * 16 + m16;
    const bf16_t* xp = X + (size_t)arow * DIM + quad * 8;
#pragma unroll
    for (int kk = 0; kk < 4; kk++) {
      bf16x8 av = {};
      if (arow < M) av = *reinterpret_cast<const bf16x8*>(xp + kk * 32);
      afrag[rt][kk] = av;
    }
  }

  int ncols = N >> 4;
  for (int nt = 0; nt < ncols; nt++) {
    int r = nt * 16 + m16;
    int bbase = r * 256 + quad * 16;               // byte offset of 16B frag
    int swz = (r & 7) << 4;
    bf16x8 bfrag[4];
#pragma unroll
    for (int kk = 0; kk < 4; kk++)
      bfrag[kk] = *reinterpret_cast<const bf16x8*>(
          (const char*)swt + ((bbase + kk * 64) ^ swz));
    float4 bias = *reinterpret_cast<const float4*>(B + nt * 16 + quad * 4);
#pragma unroll
    for (int rt = 0; rt < 4; rt++) {
      floatx4 acc = {0.f, 0.f, 0.f, 0.f};
#pragma unroll
      for (int kk = 0; kk < 4; kk++)
        acc = __builtin_amdgcn_mfma_f32_16x16x32_bf16(bfrag[kk], afrag[rt][kk], acc, 0, 0, 0);
      int row = wrow0 + rt * 16 + m16;
      if (row < M) {
        bf16x4 o;
        o[0] = (bf16_t)(acc[0] + bias.x);
        o[1] = (bf16_t)(acc[1] + bias.y);
        o[2] = (bf16_t)(acc[2] + bias.z);
        o[3] = (bf16_t)(acc[3] + bias.w);
        *reinterpret_cast<bf16x4*>(Y + (size_t)row * N + nt * 16 + quad * 4) = o;
      }
    }
  }
}

// ---------------------------------------------------------------------------
// Single-kernel parallel scan over n=54000 (53 blocks of 1024) via decoupled
// lookback (R5; neutral vs 2-kernel but fewer launches — keep). af[] zeroed
// by the arena memset. NOTE: do NOT replace with a single-block serial scan
// — measured 103 us in an earlier session.
// ---------------------------------------------------------------------------
__global__ __launch_bounds__(1024) void scan_fused(const int* __restrict__ cnt,
                                                   int* __restrict__ rp,
                                                   int* af, int n) {
  __shared__ int wsum[16];
  __shared__ int pfx_s;
  int i = blockIdx.x * 1024 + threadIdx.x;
  int lane = threadIdx.x & 63, w = threadIdx.x >> 6;
  int v = (i < n) ? cnt[i] : 0;
  int x = v;
#pragma unroll
  for (int off = 1; off < 64; off <<= 1) {
    int y = __shfl_up(x, off);
    if (lane >= off) x += y;
  }
  if (lane == 63) wsum[w] = x;
  __syncthreads();
  if (w == 0 && lane < 16) {
    int s = wsum[lane];
#pragma unroll
    for (int off = 1; off < 16; off <<= 1) {
      int y = __shfl_up(s, off);
      if (lane >= off) s += y;
    }
    wsum[lane] = s;
  }
  __syncthreads();
  int incl = x + (w ? wsum[w - 1] : 0);
  if (threadIdx.x == 0) atomicExch(af + blockIdx.x, wsum[15] + 1);  // publish
  if (w == 0) {
    int pred = 0;
    if (lane < (int)blockIdx.x) {               // blockIdx.x <= 52 < 64
      int t;
      while ((t = atomicAdd(af + lane, 0)) == 0) { __builtin_amdgcn_s_sleep(8); }
      pred = t - 1;
    }
#pragma unroll
    for (int off = 32; off > 0; off >>= 1) pred += __shfl_down(pred, off);
    if (lane == 0) pfx_s = pred;
  }
  __syncthreads();
  if (i < n) rp[i] = incl - v + pfx_s;
  if (i == 0) rp[n] = 2 * NE;                   // static total sentinel
}

// ---------------------------------------------------------------------------
// Atomic-free CSR scatter, 4 edges/thread (rank precomputed in histgemm).
// ---------------------------------------------------------------------------
#define SCAT_HALF 245               // ceil(NE/1024)
#define SCAT_B 490                  // 2 relations
struct ScArgs {
  const int* sgd; const int* gsd; const int* sgs; const int* gss;
  const float* easg; const float* eags;
  const int* rp; const unsigned short* rank_sg; const unsigned short* rank_gs;
  uint2* meta;
};

__global__ __launch_bounds__(256) void scat(ScArgs a) {
  int rel = (int)blockIdx.x >= SCAT_HALF;
  int b = (int)blockIdx.x - (rel ? SCAT_HALF : 0);
  int t4 = (b * 256 + (int)threadIdx.x) * 4;
  if (t4 < NE) {                            // NE % 4 == 0: all-or-nothing
    const int* dp = rel ? a.gsd : a.sgd;
    const int* sp = rel ? a.gss : a.sgs;
    const float* ep = rel ? a.eags : a.easg;
    const unsigned short* rk = rel ? a.rank_gs : a.rank_sg;
    const int* rpb = a.rp + (rel ? NG : 0);
    int4 d4 = *reinterpret_cast<const int4*>(dp + t4);
    int4 s4 = *reinterpret_cast<const int4*>(sp + t4);
    float4 e4 = *reinterpret_cast<const float4*>(ep + t4);
    ushort4 r4 = *reinterpret_cast<const ushort4*>(rk + t4);
    int p0 = rpb[d4.x] + (int)r4.x;         // 4 independent gather chains
    int p1 = rpb[d4.y] + (int)r4.y;
    int p2 = rpb[d4.z] + (int)r4.z;
    int p3 = rpb[d4.w] + (int)r4.w;
    uint2 v0, v1, v2, v3;
    v0.x = (unsigned)s4.x; v0.y = __float_as_uint(e4.x);
    v1.x = (unsigned)s4.y; v1.y = __float_as_uint(e4.y);
    v2.x = (unsigned)s4.z; v2.y = __float_as_uint(e4.z);
    v3.x = (unsigned)s4.w; v3.y = __float_as_uint(e4.w);
    a.meta[p0] = v0;
    a.meta[p1] = v1;
    a.meta[p2] = v2;
    a.meta[p3] = v3;
  }
}

// ---------------------------------------------------------------------------
// Multi-config MFMA GEMM (phase D), runtime column count. R2 structure,
// 2 row-tiles per wave (128 rows/block) to keep >=450 blocks.
// ---------------------------------------------------------------------------
template <int NCFG>
struct GArgs {
  const bf16_t* X[NCFG];
  const bf16_t* Wt[NCFG];
  const float* Bv[NCFG];
  bf16_t* Y[NCFG];
  int M[NCFG];
  int Ncol[NCFG];
  int blk0[NCFG];
};

template <int NCFG>
__global__ __launch_bounds__(256, 4) void gemm_multi(GArgs<NCFG> a) {
  int c = 0;
#pragma unroll
  for (int i = 1; i < NCFG; i++) if ((int)blockIdx.x >= a.blk0[i]) c = i;
  const bf16_t* X = a.X[c];
  const bf16_t* Wt = a.Wt[c];
  const float* B = a.Bv[c];
  bf16_t* Y = a.Y[c];
  int M = a.M[c];
  int N = a.Ncol[c];

  int wv = threadIdx.x >> 6, lane = threadIdx.x & 63;
  int m16 = lane & 15, quad = lane >> 4;
  int wrow0 = ((int)blockIdx.x - a.blk0[c]) * 128 + wv * 32;  // 2 row-tiles

  bf16x8 afrag[2][4];
#pragma unroll
  for (int rt = 0; rt < 2; rt++) {
    int arow = wrow0 + rt * 16 + m16;
    const bf16_t* xp = X + (size_t)arow * DIM + quad * 8;
#pragma unroll
    for (int kk = 0; kk < 4; kk++) {
      bf16x8 av = {};
      if (arow < M) av = *reinterpret_cast<const bf16x8*>(xp + kk * 32);
      afrag[rt][kk] = av;
    }
  }

  int ncols = N >> 4;
  for (int nt = 0; nt < ncols; nt++) {
    const bf16_t* bptr = Wt + (size_t)(nt * 16 + m16) * DIM + quad * 8;
    bf16x8 bfrag[4];
#pragma unroll
    for (int kk = 0; kk < 4; kk++)
      bfrag[kk] = *reinterpret_cast<const bf16x8*>(bptr + kk * 32);
    float4 bias = *reinterpret_cast<const float4*>(B + nt * 16 + quad * 4);
#pragma unroll
    for (int rt = 0; rt < 2; rt++) {
      floatx4 acc = {0.f, 0.f, 0.f, 0.f};
#pragma unroll
      for (int kk = 0; kk < 4; kk++)
        acc = __builtin_amdgcn_mfma_f32_16x16x32_bf16(bfrag[kk], afrag[rt][kk], acc, 0, 0, 0);
      int row = wrow0 + rt * 16 + m16;
      if (row < M) {
        bf16x4 o;
        o[0] = (bf16_t)(acc[0] + bias.x);
        o[1] = (bf16_t)(acc[1] + bias.y);
        o[2] = (bf16_t)(acc[2] + bias.z);
        o[3] = (bf16_t)(acc[3] + bias.w);
        *reinterpret_cast<bf16x4*>(Y + (size_t)row * N + nt * 16 + quad * 4) = o;
      }
    }
  }
}

// ---------------------------------------------------------------------------
// Fused phase-C gather, GROUP-PER-DST layout (NC=128, 8 ch per lane,
// 16-lane groups; head = gl>>2 -> logit reduce = 2 shfls, no dst select).
// Blocks [0, SGB): sg — 4 waves/block, each wave 4 dsts, one per group.
// Blocks [SGB, SGB+NS): gs — one block per dst; 16 groups walk LDS-staged
//   edges (block-coalesced meta stage), partials combined in LDS.
// NOTE: exact R2 form. R3 (2-chain unrolls inside this structure) and R4
// (wave-per-dst, no LDS) BOTH regressed ~10 us — do not re-attempt without
// per-kernel timing evidence. Also: no readfirstlane+scalar branch per edge
// (earlier measured 73 us vs 55).
// ---------------------------------------------------------------------------
#define SGB 3125                    // 50000 dsts / (4 waves * 4 dsts)
__global__ __launch_bounds__(256) void gatC(
    const int* __restrict__ rp, const uint2* __restrict__ meta,
    const float* __restrict__ WeS, const float* __restrict__ attS,
    const float* __restrict__ boS,
    const bf16_t* __restrict__ xlS, const bf16_t* __restrict__ xrS,
    bf16_t* __restrict__ outS,
    const float* __restrict__ WeG, const float* __restrict__ attG,
    const float* __restrict__ boG,
    const bf16_t* __restrict__ xlG, const bf16_t* __restrict__ xrG,
    const bf16_t* __restrict__ slG, bf16_t* __restrict__ outG) {
  __shared__ uint2 smeta[256];
  __shared__ float lacc[16][128];
  __shared__ float lden[16][4];
  int lane = threadIdx.x & 63, wv = threadIdx.x >> 6;
  int gl = lane & 15, grp = lane >> 4;

  if (blockIdx.x < SGB) {
    // ---------------- sg: 4 dsts per wave, one per 16-lane group ----------
    int wid = blockIdx.x * 4 + wv;
    int d0 = wid * 4;
    int q = lane < 5 ? lane : 0;
    int rv = rp[d0 + q];
    int beg = __shfl(rv, grp), end = __shfl(rv, grp + 1);
    int dst = d0 + grp;

    float wev[8], atv[8], xrv[8], acc[8];
    *reinterpret_cast<float4*>(wev) = *reinterpret_cast<const float4*>(WeS + gl * 8);
    *reinterpret_cast<float4*>(wev + 4) = *reinterpret_cast<const float4*>(WeS + gl * 8 + 4);
    *reinterpret_cast<float4*>(atv) = *reinterpret_cast<const float4*>(attS + gl * 8);
    *reinterpret_cast<float4*>(atv + 4) = *reinterpret_cast<const float4*>(attS + gl * 8 + 4);
    bf16x8 xrb = *reinterpret_cast<const bf16x8*>(xrS + (size_t)dst * 128 + gl * 8);
#pragma unroll
    for (int v = 0; v < 8; v++) { xrv[v] = (float)xrb[v]; acc[v] = 0.f; }
    float den = 0.f;

    for (int i0 = beg; i0 < end; i0 += 16) {
      int cnt = min(16, end - i0);
      int s_l = 0; float ea_l = 0.f;
      if (gl < cnt) {
        uint2 mv = meta[i0 + gl];
        s_l = (int)mv.x; ea_l = __uint_as_float(mv.y);
      }
      // 1-deep prefetch of next edge's row
      int base = lane & 48;
      float ea = __shfl(ea_l, base);
      bf16x8 xlb = *reinterpret_cast<const bf16x8*>(
          xlS + (size_t)__shfl(s_l, base) * 128 + gl * 8);
      for (int k = 0; k < cnt; k++) {
        bf16x8 cur = xlb;
        float eac = ea;
        if (k + 1 < cnt) {
          ea = __shfl(ea_l, base + k + 1);
          xlb = *reinterpret_cast<const bf16x8*>(
              xlS + (size_t)__shfl(s_l, base + k + 1) * 128 + gl * 8);
        }
        float p = 0.f, xf[8];
#pragma unroll
        for (int v = 0; v < 8; v++) {
          xf[v] = (float)cur[v];
          float z = fmaf(eac, wev[v], xrv[v]) + xf[v];
          z = z > 0.f ? z : 0.2f * z;            // leaky_relu(., 0.2)
          p = fmaf(z, atv[v], p);
        }
        p += __shfl_xor(p, 1);
        p += __shfl_xor(p, 2);                   // head-wide logit (4 lanes)
        float ex = __expf(p);
        den += ex;
#pragma unroll
        for (int v = 0; v < 8; v++) acc[v] = fmaf(ex, xf[v], acc[v]);
      }
    }
    float inv = den > 0.f ? 1.f / den : 0.f;
    bf16x8 o;
#pragma unroll
    for (int v = 0; v < 8; v++) {
      float val = acc[v] * inv + boS[gl * 8 + v];
      o[v] = (bf16_t)(val > 0.f ? val : 0.f);
    }
    *reinterpret_cast<bf16x8*>(outS + (size_t)dst * 128 + gl * 8) = o;
  } else {
    // ---------------- gs: one block per dst, 16 groups over LDS stage -----
    int d = (int)blockIdx.x - SGB;
    const int* rpg = rp + NG;
    int G = wv * 4 + grp;
    int tid = threadIdx.x;

    float wev[8], atv[8], xrv[8], acc[8];
    *reinterpret_cast<float4*>(wev) = *reinterpret_cast<const float4*>(WeG + gl * 8);
    *reinterpret_cast<float4*>(wev + 4) = *reinterpret_cast<const float4*>(WeG + gl * 8 + 4);
    *reinterpret_cast<float4*>(atv) = *reinterpret_cast<const float4*>(attG + gl * 8);
    *reinterpret_cast<float4*>(atv + 4) = *reinterpret_cast<const float4*>(attG + gl * 8 + 4);
    bf16x8 xrb = *reinterpret_cast<const bf16x8*>(xrG + (size_t)d * 128 + gl * 8);
#pragma unroll
    for (int v = 0; v < 8; v++) { xrv[v] = (float)xrb[v]; acc[v] = 0.f; }
    float den = 0.f;

    int beg = rpg[d], end = rpg[d + 1];
    for (int base = beg; base < end; base += 256) {
      int cntb = min(256, end - base);
      __syncthreads();
      if (tid < cntb) smeta[tid] = meta[base + tid];
      __syncthreads();
      int e = G;
      uint2 mv; bf16x8 xlb;
      if (e < cntb) {
        mv = smeta[e];
        xlb = *reinterpret_cast<const bf16x8*>(xlG + (size_t)mv.x * 128 + gl * 8);
      }
      while (e < cntb) {
        bf16x8 cur = xlb;
        float eac = __uint_as_float(mv.y);
        int en = e + 16;
        if (en < cntb) {
          mv = smeta[en];
          xlb = *reinterpret_cast<const bf16x8*>(xlG + (size_t)mv.x * 128 + gl * 8);
        }
        float p = 0.f, xf[8];
#pragma unroll
        for (int v = 0; v < 8; v++) {
          xf[v] = (float)cur[v];
          float z = fmaf(eac, wev[v], xrv[v]) + xf[v];
          z = z > 0.f ? z : 0.2f * z;
          p = fmaf(z, atv[v], p);
        }
        p += __shfl_xor(p, 1);
        p += __shfl_xor(p, 2);
        float ex = __expf(p);
        den += ex;
#pragma unroll
        for (int v = 0; v < 8; v++) acc[v] = fmaf(ex, xf[v], acc[v]);
        e = en;
      }
    }
#pragma unroll
    for (int v = 0; v < 8; v++) lacc[G][gl * 8 + v] = acc[v];
    if ((gl & 3) == 0) lden[G][gl >> 2] = den;
    __syncthreads();
    if (wv != 0) return;
    int ch = lane * 2;
    int h = lane >> 4;
    float a0 = 0.f, a1 = 0.f, dh = 0.f;
#pragma unroll
    for (int g2 = 0; g2 < 16; g2++) {
      a0 += lacc[g2][ch];
      a1 += lacc[g2][ch + 1];
      dh += lden[g2][h];
    }
    float inv = dh > 0.f ? 1.f / dh : 0.f;
    float v0 = a0 * inv + boG[ch] + (float)slG[(size_t)d * 32 + (ch & 31)];
    float v1 = a1 * inv + boG[ch + 1] + (float)slG[(size_t)d * 32 + ((ch + 1) & 31)];
    bf16x2 o;
    o[0] = (bf16_t)(v0 > 0.f ? v0 : 0.f);
    o[1] = (bf16_t)(v1 > 0.f ? v1 : 0.f);
    *reinterpret_cast<bf16x2*>(outG + (size_t)d * 128 + ch) = o;
  }
}

// ---------------------------------------------------------------------------
// Phase-E gather: one block per dst; 16 groups of 16 lanes, 16 ch/lane
// (NC=256); LDS-staged edges + LDS combine; head-mean epilogue -> fp32 out.
// Exact R2 form (see gatC note: R3/R4 variants regressed).
// ---------------------------------------------------------------------------
__global__ __launch_bounds__(256) void gatE(
    const int* __restrict__ rp, const uint2* __restrict__ meta,
    const float* __restrict__ We, const float* __restrict__ att,
    const bf16_t* __restrict__ xl, const bf16_t* __restrict__ xr,
    const float* __restrict__ bo, const bf16_t* __restrict__ sl,
    float* __restrict__ out) {
  __shared__ uint2 smeta[256];
  __shared__ float lacc[16][256];
  __shared__ float lden[16][4];
  int lane = threadIdx.x & 63, wv = threadIdx.x >> 6;
  int gl = lane & 15, grp = lane >> 4;
  int G = wv * 4 + grp;
  int tid = threadIdx.x;
  int d = blockIdx.x;

  float wev[16], atv[16], xrv[16], acc[16];
#pragma unroll
  for (int b = 0; b < 4; b++) {
    *reinterpret_cast<float4*>(wev + b * 4) =
        *reinterpret_cast<const float4*>(We + gl * 16 + b * 4);
    *reinterpret_cast<float4*>(atv + b * 4) =
        *reinterpret_cast<const float4*>(att + gl * 16 + b * 4);
  }
  {
    bf16x8 r0 = *reinterpret_cast<const bf16x8*>(xr + (size_t)d * 256 + gl * 16);
    bf16x8 r1 = *reinterpret_cast<const bf16x8*>(xr + (size_t)d * 256 + gl * 16 + 8);
#pragma unroll
    for (int v = 0; v < 8; v++) { xrv[v] = (float)r0[v]; xrv[v + 8] = (float)r1[v]; }
  }
#pragma unroll
  for (int v = 0; v < 16; v++) acc[v] = 0.f;
  float den = 0.f;

  int beg = rp[d], end = rp[d + 1];
  for (int base = beg; base < end; base += 256) {
    int cntb = min(256, end - base);
    __syncthreads();
    if (tid < cntb) smeta[tid] = meta[base + tid];
    __syncthreads();
    int e = G;
    uint2 mv; bf16x8 x0, x1;
    if (e < cntb) {
      mv = smeta[e];
      x0 = *reinterpret_cast<const bf16x8*>(xl + (size_t)mv.x * 256 + gl * 16);
      x1 = *reinterpret_cast<const bf16x8*>(xl + (size_t)mv.x * 256 + gl * 16 + 8);
    }
    while (e < cntb) {
      bf16x8 c0 = x0, c1 = x1;
      float eac = __uint_as_float(mv.y);
      int en = e + 16;
      if (en < cntb) {
        mv = smeta[en];
        x0 = *reinterpret_cast<const bf16x8*>(xl + (size_t)mv.x * 256 + gl * 16);
        x1 = *reinterpret_cast<const bf16x8*>(xl + (size_t)mv.x * 256 + gl * 16 + 8);
      }
      float p = 0.f, xf[16];
#pragma unroll
      for (int v = 0; v < 8; v++) { xf[v] = (float)c0[v]; xf[v + 8] = (float)c1[v]; }
#pragma unroll
      for (int v = 0; v < 16; v++) {
        float z = fmaf(eac, wev[v], xrv[v]) + xf[v];
        z = z > 0.f ? z : 0.2f * z;              // leaky_relu(., 0.2)
        p = fmaf(z, atv[v], p);
      }
      p += __shfl_xor(p, 1);
      p += __shfl_xor(p, 2);                     // head-wide logit (4 lanes)
      float ex = __expf(p);
      den += ex;
#pragma unroll
      for (int v = 0; v < 16; v++) acc[v] = fmaf(ex, xf[v], acc[v]);
      e = en;
    }
  }
#pragma unroll
  for (int v = 0; v < 16; v++) lacc[G][gl * 16 + v] = acc[v];
  if ((gl & 3) == 0) lden[G][gl >> 2] = den;
  __syncthreads();
  if (wv != 0) return;
  int ch = lane * 4;
  int h = lane >> 4;
  float a[4] = {0.f, 0.f, 0.f, 0.f};
  float dh = 0.f;
#pragma unroll
  for (int g2 = 0; g2 < 16; g2++) {
#pragma unroll
    for (int v = 0; v < 4; v++) a[v] += lacc[g2][ch + v];
    dh += lden[g2][h];
  }
  float inv = dh > 0.f ? 1.f / dh : 0.f;
#pragma unroll
  for (int v = 0; v < 4; v++) {
    float s_ = a[v] * inv;
    s_ += __shfl_xor(s_, 16);
    s_ += __shfl_xor(s_, 32);                    // sum over the 4 heads
    if (lane < 16) {
      int c = (lane & 15) * 4 + v;
      float val = 0.25f * s_ + bo[c] + (float)sl[(size_t)d * 64 + c];
      out[(size_t)d * 64 + c] = val > 0.f ? val : 0.f;
    }
  }
}

// ---------------------------------------------------------------------------

static inline int nblk(long long threads) { return (int)((threads + 255) / 256); }
static inline int nrow(int M, int R) { return (M + R - 1) / R; }

extern "C" void kernel_launch(void* const* d_in, const int* in_sizes, int n_in,
                              void* d_out, int out_size, void* d_ws, size_t ws_size,
                              hipStream_t stream) {
  const float* x_mrna = (const float*)d_in[0];
  const float* x_gene = (const float*)d_in[1];
  const int* sg_src = (const int*)d_in[2];
  const int* sg_dst = (const int*)d_in[3];
  const int* gs_src = (const int*)d_in[4];
  const int* gs_dst = (const int*)d_in[5];
  const float* ea_sg = (const float*)d_in[6];
  const float* ea_gs = (const float*)d_in[7];
  const float* Wl1_sg = (const float*)d_in[8];
  const float* bl1_sg = (const float*)d_in[9];
  const float* Wr1_sg = (const float*)d_in[10];
  const float* br1_sg = (const float*)d_in[11];
  const float* We1_sg = (const float*)d_in[12];
  const float* att1_sg = (const float*)d_in[13];
  const float* bo1_sg = (const float*)d_in[14];
  const float* Wl1_gs = (const float*)d_in[15];
  const float* bl1_gs = (const float*)d_in[16];
  const float* Wr1_gs = (const float*)d_in[17];
  const float* br1_gs = (const float*)d_in[18];
  const float* We1_gs = (const float*)d_in[19];
  const float* att1_gs = (const float*)d_in[20];
  const float* bo1_gs = (const float*)d_in[21];
  const float* Wl3_gs = (const float*)d_in[22];
  const float* bl3_gs = (const float*)d_in[23];
  const float* Wr3_gs = (const float*)d_in[24];
  const float* br3_gs = (const float*)d_in[25];
  const float* We3_gs = (const float*)d_in[26];
  const float* att3_gs = (const float*)d_in[27];
  const float* bo3_gs = (const float*)d_in[28];
  const float* Wsl1 = (const float*)d_in[29];
  const float* bsl1 = (const float*)d_in[30];
  const float* Wsl3 = (const float*)d_in[31];
  const float* bsl3 = (const float*)d_in[32];

  // ---- workspace arena (fp32 element offsets), bf16 throughout ----
  float* ws = (float*)d_ws;
  bf16_t* xl1_gs = (bf16_t*)(ws + 0);        // bf16[50000*128] dead after C
  bf16_t* xl1_sg = (bf16_t*)(ws + 3200000);  // bf16[4000*128]  dead after C
  bf16_t* xr1_sg = (bf16_t*)(ws + 3456000);  // bf16[50000*128] dead after C
  bf16_t* xr1_gs = (bf16_t*)(ws + 6656000);  // bf16[4000*128]  dead after C
  bf16_t* xl3    = (bf16_t*)(ws + 0);        // bf16[50000*256] aliases [0,6.4M)
  bf16_t* xr3    = (bf16_t*)(ws + 6400000);  // bf16[4000*256]  aliases tail
  bf16_t* xb_mrna = (bf16_t*)(ws + 6912000); // bf16[4000*128]
  bf16_t* xb_gene = (bf16_t*)(ws + 7168000); // bf16[50000*128]
  bf16_t* x1_gene = (bf16_t*)(ws + 10368000);// bf16[50000*128]
  bf16_t* x1_mrna = (bf16_t*)(ws + 13568000);// bf16[4000*128]
  bf16_t* sl1    = (bf16_t*)(ws + 13824000); // bf16[4000*32]
  bf16_t* sl3    = (bf16_t*)(ws + 13856000); // bf16[4000*64]
  int*   ib      = (int*)(ws + 13920000);
  int* cnt  = ib + 0;                   // [54000] zeroed by memset
  int* af   = ib + 54000;               // [64] lookback agg+flag, zeroed too
  int* rpc  = ib + 54064;               // [54001]
  unsigned short* rank_sg = (unsigned short*)(ib + 108066);  // [250000]
  unsigned short* rank_gs = (unsigned short*)(ib + 233066);  // [250000]
  uint2* meta = (uint2*)(ib + 358066);  // [500000] packed (src, ea), 8B-aligned
  bf16_t* wtb = (bf16_t*)(ib + 1358066);// [143360] bf16 transposed weights
  // end: ib + 1429746 ints -> total ~61.4 MB

  bf16_t* wt_l1sg = wtb + 0;
  bf16_t* wt_r1sg = wtb + 16384;
  bf16_t* wt_l1gs = wtb + 32768;
  bf16_t* wt_r1gs = wtb + 49152;
  bf16_t* wt_l3   = wtb + 65536;   // [256*128]
  bf16_t* wt_r3   = wtb + 98304;   // [256*128]
  bf16_t* wt_sl1  = wtb + 131072;  // [32*128]
  bf16_t* wt_sl3  = wtb + 135168;  // [64*128]

  // zero histogram counters + lookback flags (ws poisoned 0xAA per call)
  hipMemsetAsync(cnt, 0, (54000 + 64) * sizeof(int), stream);

  // ---- phase A0: weight transposes + bf16 casts (feeds the L1 GEMMs) ----
  {
    PArgs pa;
    const float* Wsrc[8] = {Wl1_sg, Wr1_sg, Wl1_gs, Wr1_gs, Wl3_gs, Wr3_gs, Wsl1, Wsl3};
    bf16_t* Wdst[8] = {wt_l1sg, wt_r1sg, wt_l1gs, wt_r1gs, wt_l3, wt_r3, wt_sl1, wt_sl3};
    int Nn[8] = {128, 128, 128, 128, 256, 256, 32, 64};
    int e0[8] = {0, 16384, 32768, 49152, 65536, 98304, 131072, 135168};
    for (int i = 0; i < 8; i++) { pa.W[i] = Wsrc[i]; pa.Wt[i] = Wdst[i]; pa.N[i] = Nn[i]; pa.e0[i] = e0[i]; }
    pa.xm = x_mrna; pa.xbm = xb_mrna;
    pa.xg = x_gene; pa.xbg = xb_gene;
    prep<<<PREP_B, 256, 0, stream>>>(pa);
  }

  // ---- phase A1: histogram(+rank) OVERLAPPED with the 5 L1 GEMMs ----
  {
    HGArgs hg;
    hg.sgd = sg_dst; hg.gsd = gs_dst;
    hg.cnt = cnt; hg.rank_sg = rank_sg; hg.rank_gs = rank_gs;
    const bf16_t* Xs[5] = {xb_mrna, xb_gene, xb_gene, xb_mrna, xb_mrna};
    const bf16_t* Ws[5] = {wt_l1sg, wt_r1sg, wt_l1gs, wt_r1gs, wt_sl1};
    const float* Bs[5] = {bl1_sg, br1_sg, bl1_gs, br1_gs, bsl1};
    bf16_t* Ys[5] = {xl1_sg, xr1_sg, xl1_gs, xr1_gs, sl1};
    int Ms[5] = {NS, NG, NG, NS, NS};
    int Ns[5] = {128, 128, 128, 128, 32};
    int b0 = 0;
    for (int i = 0; i < 5; i++) {
      hg.X[i] = Xs[i]; hg.Wt[i] = Ws[i]; hg.Bv[i] = Bs[i]; hg.Y[i] = Ys[i];
      hg.M[i] = Ms[i]; hg.Ncol[i] = Ns[i]; hg.blk0[i] = b0;
      b0 += nrow(Ms[i], 256);
    }
    hg.hist0 = b0;                                   // 440
    histgemm<<<b0 + HIST_B, 256, 0, stream>>>(hg);   // 440 + 977 blocks
  }

  // ---- phase A2: single-kernel lookback scan ----
  int nchunks = (NDST_TOT + 1023) / 1024;            // 53
  scan_fused<<<nchunks, 1024, 0, stream>>>(cnt, rpc, af, NDST_TOT);

  // ---- phase B: atomic-free scatter (4 edges/thread) ----
  {
    ScArgs sa;
    sa.sgd = sg_dst; sa.gsd = gs_dst; sa.sgs = sg_src; sa.gss = gs_src;
    sa.easg = ea_sg; sa.eags = ea_gs;
    sa.rp = rpc; sa.rank_sg = rank_sg; sa.rank_gs = rank_gs; sa.meta = meta;
    scat<<<SCAT_B, 256, 0, stream>>>(sa);            // 490 blocks
  }

  // ---- phase C: fused layer-1 gathers ----
  gatC<<<SGB + NS, 256, 0, stream>>>(
      rpc, meta,
      We1_sg, att1_sg, bo1_sg, xl1_sg, xr1_sg, x1_gene,
      We1_gs, att1_gs, bo1_gs, xl1_gs, xr1_gs, sl1, x1_mrna);

  // ---- phase D: 3 fused layer-3 GEMMs (incl. sl3), 128 rows/block ----
  {
    GArgs<3> ga;
    const bf16_t* Xs[3] = {x1_gene, x1_mrna, x1_mrna};
    const bf16_t* Ws[3] = {wt_l3, wt_r3, wt_sl3};
    const float* Bs[3] = {bl3_gs, br3_gs, bsl3};
    bf16_t* Ys[3] = {xl3, xr3, sl3};
    int Ms[3] = {NG, NS, NS};
    int Ns[3] = {256, 256, 64};
    int b0 = 0;
    for (int i = 0; i < 3; i++) {
      ga.X[i] = Xs[i]; ga.Wt[i] = Ws[i]; ga.Bv[i] = Bs[i]; ga.Y[i] = Ys[i];
      ga.M[i] = Ms[i]; ga.Ncol[i] = Ns[i]; ga.blk0[i] = b0;
      b0 += nrow(Ms[i], 128);
    }
    gemm_multi<3><<<b0, 256, 0, stream>>>(ga);   // 455 blocks
  }

  // ---- phase E: layer-3 gather (head-mean/self-loop/relu) -> d_out ----
  gatE<<<NS, 256, 0, stream>>>(rpc + NG, meta, We3_gs, att3_gs,
                               xl3, xr3, bo3_gs, sl3, (float*)d_out);
}